// Round 6
// baseline (131.712 us; speedup 1.0000x reference)
//
#include <hip/hip_runtime.h>

// Problem constants (reference: B,H,I,E = 16,16,512,512)
#define B_ 16
#define H_ 16
#define I_ 512
#define E_ 512

// Algebraic collapse (verified earlier rounds, absmax <= 0.25):
//   softmax(axis=2) followed by sum(axis=2) makes attention exact identity on V:
//   emb[b,h,e] = sum_i x[b,i,e] * W_v[h,i,e];  out = emb @ mlp_w^T + mlp_b.
//
// Ledger: R1 grid.sync ~50us each -> dead. R2 device fences serialize -> dead.
// R4 mlp swizzle rebuild = neutral (fill noise +-2-3us masks <5us changes).
// R5 single-read emb at 128 blocks = -3.4us REGRESSION: half the CUs idle,
// 32MB HBM read from half chip. Fixed overhead ~87us (two 256MB poison
// fills at 80-85% HBM peak = harness roofline); addressable ~25us.
// This round (bundle, predicted -6..-9us):
//  (1) emb: full-chip 256 blocks (8 etile x 2 bhalf x 16 slices); x single-
//      read, Wv read 2x but concurrent siblings -> 2nd read L3-hit.
//  (2) mlp: full-K (8 staged chunks, verified R4 swizzle), fused bias+out
//      write -> kernel 4 and the 8MB mpart round-trip deleted.
//  (3) pipeline: 3 kernels, 2 boundaries.

#define NSLICE 16   // i-slices for emb partials (32 i's each)

// ---------------------------------------------------------------------------
// Kernel 1: partial emb, full-chip near-single-read version.
// Grid (E/64=8, 2 b-halves, NSLICE=16) = 256 blocks, 256 threads.
// Block: 8b x 16h x 64e (lane=e) x 32i, staged in 4 LDS chunks of 8 i.
// Wave w owns 4 h's (h = w*4..w*4+3); acc 8b x 4h per thread.
// LDS 48 KB: xs[8][8][64] (16K) + ws[8][16][64] (32K).
//   staging: float4 coalesced (16 consecutive threads = one 64-float row);
//   inner reads: 64-lane stride-1 b32 rows (2 lanes/bank = free).
// Per wave-i: 12 ds_read_b32 + 32 fma (64 fma-cyc) -> compute-bound inner.
// ---------------------------------------------------------------------------
__global__ __launch_bounds__(256) void k_emb_part(const float* __restrict__ x,
                                                  const float* __restrict__ Wv,
                                                  float* __restrict__ part) {
    const int etile = blockIdx.x;         // 0..7
    const int b0    = blockIdx.y * 8;     // 0 or 8
    const int slice = blockIdx.z;         // 0..15
    const int t     = (int)threadIdx.x;
    const int lane  = t & 63;
    const int wave  = t >> 6;             // 0..3
    const int e     = etile * 64 + lane;
    const int hw0   = wave * 4;           // this wave's 4 h's

    __shared__ float xs[8][8][64];        // [ii][b][e]  16 KB
    __shared__ float ws[8][16][64];       // [ii][h][e]  32 KB

    float acc[8][4];
#pragma unroll
    for (int bi = 0; bi < 8; ++bi)
#pragma unroll
        for (int hj = 0; hj < 4; ++hj) acc[bi][hj] = 0.0f;

    const int ibase0 = slice * 32;

    for (int chunk = 0; chunk < 4; ++chunk) {
        const int ib = ibase0 + chunk * 8;
        if (chunk) __syncthreads();       // protect LDS reuse across chunks

        // stage xs: 8b x 8i x 64e = 1024 float4 -> 4/thread.
#pragma unroll
        for (int it2 = 0; it2 < 4; ++it2) {
            const int f  = t + it2 * 256;
            const int ii = f >> 7;                // 0..7
            const int bb = (f >> 4) & 7;          // 0..7
            const int eq = f & 15;
            float4 v = *(const float4*)(
                x + ((size_t)(b0 + bb) * I_ + (ib + ii)) * E_ + etile * 64 + eq * 4);
            *(float4*)&xs[ii][bb][eq * 4] = v;
        }
        // stage ws: 16h x 8i x 64e = 2048 float4 -> 8/thread.
#pragma unroll
        for (int it2 = 0; it2 < 8; ++it2) {
            const int f  = t + it2 * 256;
            const int ii = f >> 8;                // 0..7
            const int hh = (f >> 4) & 15;         // 0..15
            const int eq = f & 15;
            float4 v = *(const float4*)(
                Wv + ((size_t)hh * I_ + (ib + ii)) * E_ + etile * 64 + eq * 4);
            *(float4*)&ws[ii][hh][eq * 4] = v;
        }
        __syncthreads();

#pragma unroll
        for (int ii = 0; ii < 8; ++ii) {
            float xv[8], wv[4];
#pragma unroll
            for (int bi = 0; bi < 8; ++bi) xv[bi] = xs[ii][bi][lane];
#pragma unroll
            for (int hj = 0; hj < 4; ++hj) wv[hj] = ws[ii][hw0 + hj][lane];
#pragma unroll
            for (int bi = 0; bi < 8; ++bi)
#pragma unroll
                for (int hj = 0; hj < 4; ++hj)
                    acc[bi][hj] = fmaf(xv[bi], wv[hj], acc[bi][hj]);
        }
    }

    // direct partial store: 32 rows x 64 e per wave, coalesced b32 rows.
#pragma unroll
    for (int bi = 0; bi < 8; ++bi)
#pragma unroll
        for (int hj = 0; hj < 4; ++hj) {
            const int row = (b0 + bi) * H_ + hw0 + hj;
            part[((size_t)slice * (B_ * H_) + row) * E_ + e] = acc[bi][hj];
        }
}

// ---------------------------------------------------------------------------
// Kernel 2: emb = sum of NSLICE partial slices (float4 lanes). (unchanged)
// ---------------------------------------------------------------------------
__global__ __launch_bounds__(256) void k_emb_reduce(const float4* __restrict__ part,
                                                    float4* __restrict__ emb) {
    const int idx = blockIdx.x * 256 + threadIdx.x;
    const int sl  = (B_ * H_ * E_) / 4;
    float4 s = part[idx];
#pragma unroll
    for (int j = 1; j < NSLICE; ++j) {
        float4 p = part[(size_t)j * sl + idx];
        s.x += p.x; s.y += p.y; s.z += p.z; s.w += p.w;
    }
    emb[idx] = s;
}

// ---------------------------------------------------------------------------
// Kernel 3: full-K GEMM + bias, writes out directly (k_out deleted).
// out-tile 32r x 64c, k=512 in 8 staged chunks of 64, 2x4 micro, 256 thr.
// Grid (E/64=8, 256rows/32=8) = 64 blocks.
// Staging per chunk = R4's verified XOR quad-swizzle (<=2-way everywhere).
// k ascends 0..511 sequentially -> accumulation order identical to the R4
// split-K + ordered-sum pipeline; bias added last as before.
// ---------------------------------------------------------------------------
__global__ __launch_bounds__(256) void k_mlp_full(const float* __restrict__ emb,
                                                  const float* __restrict__ W,
                                                  const float* __restrict__ bias,
                                                  float* __restrict__ out) {
    const int cblk = blockIdx.x;   // 64-col tile, 0..7
    const int rblk = blockIdx.y;   // 32-row tile, 0..7

    __shared__ float As[32][68];   // [r][swizzled k]    8.7 KB
    __shared__ float Ws[64][68];   // [k][swizzled c]   17.4 KB

    const int t  = threadIdx.x;
    const int tx = t & 15, ty = t >> 4;   // c-quad 0..15, r-pair 0..15
    const int c0 = tx * 4, r0 = ty * 2;

    float4 acc0 = {0, 0, 0, 0}, acc1 = {0, 0, 0, 0};

    for (int kc = 0; kc < 8; ++kc) {
        const int k0 = kc * 64;
        if (kc) __syncthreads();

        // stage A: 32r x 64k = 512 float4 -> 2/thread, coalesced along k.
#pragma unroll
        for (int it = 0; it < 2; ++it) {
            const int f = t + it * 256;
            const int r = f >> 4, kq = f & 15;
            float4 v = *(const float4*)(emb + (size_t)(rblk * 32 + r) * E_ + k0 + kq * 4);
            *(float4*)&As[r][((kq ^ (r >> 2)) & 15) * 4] = v;
        }
        // stage W transposed: 64c x 64k = 1024 float4 -> 4/thread.
#pragma unroll
        for (int it = 0; it < 4; ++it) {
            const int f = t + it * 256;
            const int c = f >> 4, kq = f & 15;
            float4 v = *(const float4*)(W + (size_t)(cblk * 64 + c) * E_ + k0 + kq * 4);
            const int pc = (((c >> 2) ^ kq) & 15) * 4 + (c & 3);
            Ws[kq * 4 + 0][pc] = v.x;
            Ws[kq * 4 + 1][pc] = v.y;
            Ws[kq * 4 + 2][pc] = v.z;
            Ws[kq * 4 + 3][pc] = v.w;
        }
        __syncthreads();

        for (int k = 0; k < 64; k += 4) {
            const int K  = k >> 2;
            // rows r0, r0+1 share (r>>2) == (ty>>1); Ws rows k..k+3 share K.
            const int ac = ((K ^ (ty >> 1)) & 15) * 4;
            const int wc = ((tx ^ K) & 15) * 4;
            float4 a0 = *(const float4*)&As[r0 + 0][ac];
            float4 a1 = *(const float4*)&As[r0 + 1][ac];
            float4 w0 = *(const float4*)&Ws[k + 0][wc];
            float4 w1 = *(const float4*)&Ws[k + 1][wc];
            float4 w2 = *(const float4*)&Ws[k + 2][wc];
            float4 w3 = *(const float4*)&Ws[k + 3][wc];
#define MLP_STEP(ACC, AV)                                                  \
            ACC.x = fmaf(AV.x, w0.x, fmaf(AV.y, w1.x, fmaf(AV.z, w2.x, fmaf(AV.w, w3.x, ACC.x)))); \
            ACC.y = fmaf(AV.x, w0.y, fmaf(AV.y, w1.y, fmaf(AV.z, w2.y, fmaf(AV.w, w3.y, ACC.y)))); \
            ACC.z = fmaf(AV.x, w0.z, fmaf(AV.y, w1.z, fmaf(AV.z, w2.z, fmaf(AV.w, w3.z, ACC.z)))); \
            ACC.w = fmaf(AV.x, w0.w, fmaf(AV.y, w1.w, fmaf(AV.z, w2.w, fmaf(AV.w, w3.w, ACC.w))));
            MLP_STEP(acc0, a0)
            MLP_STEP(acc1, a1)
#undef MLP_STEP
        }
    }

    // fused epilogue: bias + direct out write.
    const float4 bv = *(const float4*)(bias + cblk * 64 + c0);
    acc0.x += bv.x; acc0.y += bv.y; acc0.z += bv.z; acc0.w += bv.w;
    acc1.x += bv.x; acc1.y += bv.y; acc1.z += bv.z; acc1.w += bv.w;

    float* o = out + (size_t)(rblk * 32 + r0) * E_ + cblk * 64 + c0;
    *(float4*)(o + 0 * E_) = acc0;
    *(float4*)(o + 1 * E_) = acc1;
}

extern "C" void kernel_launch(void* const* d_in, const int* in_sizes, int n_in,
                              void* d_out, int out_size, void* d_ws, size_t ws_size,
                              hipStream_t stream) {
    // setup_inputs order: x, W_q, W_k, W_v, mlp_w, mlp_b  (all fp32)
    const float* x     = (const float*)d_in[0];
    const float* W_v   = (const float*)d_in[3];
    const float* mlp_w = (const float*)d_in[4];
    const float* mlp_b = (const float*)d_in[5];
    float* out = (float*)d_out;

    // ws layout: emb partials (16 x 256 x 512 = 8 MB) | emb (512 KB)
    float* epart = (float*)d_ws;
    float* emb   = epart + (size_t)NSLICE * B_ * H_ * E_;

    dim3 g1(E_ / 64, 2, NSLICE);                   // (8,2,16) = 256 blocks
    k_emb_part<<<g1, 256, 0, stream>>>(x, W_v, epart);

    k_emb_reduce<<<(B_ * H_ * E_ / 4) / 256, 256, 0, stream>>>(
        (const float4*)epart, (float4*)emb);

    dim3 g3(E_ / 64, (B_ * H_) / 32);              // (8,8) = 64 blocks
    k_mlp_full<<<g3, 256, 0, stream>>>(emb, mlp_w, mlp_b, out);
}

// Round 7
// 111.027 us; speedup vs baseline: 1.1863x; 1.1863x over previous
//
#include <hip/hip_runtime.h>

// Problem constants (reference: B,H,I,E = 16,16,512,512)
#define B_ 16
#define H_ 16
#define I_ 512
#define E_ 512

// Algebraic collapse (verified earlier rounds, absmax <= 0.25):
//   softmax(axis=2) followed by sum(axis=2) makes attention exact identity on V:
//   emb[b,h,e] = sum_i x[b,i,e] * W_v[h,i,e];  out = emb @ mlp_w^T + mlp_b.
//
// Ledger (6 rounds):
//  R1 cooperative grid.sync: ~50us each on 8-XCD gfx950 -> dead.
//  R2 device-scope fences (split-K last-block-done): L2 wb/inv serializes,
//     k_mlp_part 47us -> dead. Dependencies stay on launch boundaries.
//  R4 mlp 64x64x64 swizzle rebuild: neutral (fill noise +-2-3us).
//  R5 single-read LDS emb @128 blocks: -3.4us (half chip idle).
//  R6 full-chip LDS emb + full-K mlp: -19us. LDS-staged emb is LDS-pipe-
//     bound (12 ds_read per 32 fma, shared pipe) vs direct-global register
//     tiling (4:1 fma:load, L3 serves the 2x redundancy, siblings co-XCD).
//     Full-K mlp @64 blocks serializes staging with 1 block/CU. Both dead.
//  => This file: exact revert to the best-verified configuration (R4,
//     112.81us). Timed window = ~87us harness poison fills running at
//     81-85% HBM peak (their own roofline) + ~25us pipeline whose floor
//     arithmetic (~33MB compulsory HBM + compute + boundaries) leaves only
//     sub-noise headroom.

#define NSLICE 16   // i-slices for emb partials (32 i's each)
#define KSPLIT 8    // k-split for mlp partials (64 k's each)

// ---------------------------------------------------------------------------
// Kernel 1: partial emb with 8x8 register blocking, direct-from-global.
// Block: 8 b's x 8 h's x 64 e's (lane=e), one slice of 32 i's split 8/wave.
// Grid (E/64=8, B/8=2, (H/8=2)*16 slices=32) = 512 blocks, 256 threads.
// x/Wv-sharing sibling blocks are 8/16 apart in linear bid -> co-XCD under
// round-robin dispatch; the 2x logical re-read is an L2/L3 hit.
// ---------------------------------------------------------------------------
__global__ __launch_bounds__(256) void k_emb_part(const float* __restrict__ x,
                                                  const float* __restrict__ Wv,
                                                  float* __restrict__ part) {
    const int e     = blockIdx.x * 64 + (threadIdx.x & 63);
    const int b0    = blockIdx.y * 8;
    const int h0    = (blockIdx.z & 1) * 8;
    const int slice = blockIdx.z >> 1;        // 0..15
    const int lane  = threadIdx.x & 63;
    const int wave  = threadIdx.x >> 6;       // 0..3

    float acc[8][8];
#pragma unroll
    for (int bi = 0; bi < 8; ++bi)
#pragma unroll
        for (int hj = 0; hj < 8; ++hj) acc[bi][hj] = 0.0f;

    const int ibase = slice * 32 + wave * 8;
    const float* xp[8];
    const float* wp[8];
#pragma unroll
    for (int bi = 0; bi < 8; ++bi)
        xp[bi] = x + ((size_t)(b0 + bi) * I_ + ibase) * E_ + e;
#pragma unroll
    for (int hj = 0; hj < 8; ++hj)
        wp[hj] = Wv + ((size_t)(h0 + hj) * I_ + ibase) * E_ + e;

    for (int ii = 0; ii < 8; ++ii) {
        const int off = ii * E_;
        float xv[8], wv[8];
#pragma unroll
        for (int bi = 0; bi < 8; ++bi) xv[bi] = xp[bi][off];
#pragma unroll
        for (int hj = 0; hj < 8; ++hj) wv[hj] = wp[hj][off];
#pragma unroll
        for (int bi = 0; bi < 8; ++bi)
#pragma unroll
            for (int hj = 0; hj < 8; ++hj)
                acc[bi][hj] = fmaf(xv[bi], wv[hj], acc[bi][hj]);
    }

    // cross-wave reduce (4 i-subslices) through LDS; stride-1 in lane ->
    // conflict-free.
    __shared__ float red[4][64][64];  // 64 KB -> 2 blocks/CU
#pragma unroll
    for (int bi = 0; bi < 8; ++bi)
#pragma unroll
        for (int hj = 0; hj < 8; ++hj)
            red[wave][bi * 8 + hj][lane] = acc[bi][hj];
    __syncthreads();

    for (int t = threadIdx.x; t < 64 * 64; t += 256) {
        const int pair = t >> 6, le = t & 63;
        float s = (red[0][pair][le] + red[1][pair][le]) +
                  (red[2][pair][le] + red[3][pair][le]);
        const int row = (b0 + (pair >> 3)) * H_ + h0 + (pair & 7);
        part[((size_t)slice * (B_ * H_) + row) * E_ + blockIdx.x * 64 + le] = s;
    }
}

// ---------------------------------------------------------------------------
// Kernel 2: emb = sum of NSLICE partial slices (float4 lanes).
// ---------------------------------------------------------------------------
__global__ __launch_bounds__(256) void k_emb_reduce(const float4* __restrict__ part,
                                                    float4* __restrict__ emb) {
    const int idx = blockIdx.x * 256 + threadIdx.x;
    const int sl  = (B_ * H_ * E_) / 4;
    float4 s = part[idx];
#pragma unroll
    for (int j = 1; j < NSLICE; ++j) {
        float4 p = part[(size_t)j * sl + idx];
        s.x += p.x; s.y += p.y; s.z += p.z; s.w += p.w;
    }
    emb[idx] = s;
}

// ---------------------------------------------------------------------------
// Kernel 3: K-split GEMM partials (R2 rebuild, verified R4).
// out-tile 64r x 64c, k-chunk 64, 4x4 micro, 256 threads.
// Grid (E/64=8, 256rows/64=4, KSPLIT=8) = 256 blocks.
// XOR quad-swizzled LDS on both write and read sides, <=2-way everywhere.
// ---------------------------------------------------------------------------
__global__ __launch_bounds__(256) void k_mlp_part(const float* __restrict__ emb,
                                                  const float* __restrict__ W,
                                                  float* __restrict__ part) {
    const int cblk = blockIdx.x;   // 64-col tile, 0..7
    const int rblk = blockIdx.y;   // 64-row tile, 0..3
    const int kch  = blockIdx.z;   // 0..7
    const int k0   = kch * 64;

    __shared__ float As[64][68];   // [r][swizzled k]   17.4 KB
    __shared__ float Ws[64][68];   // [k][swizzled c]   17.4 KB

    const int t = threadIdx.x;

#pragma unroll
    for (int it = 0; it < 4; ++it) {
        const int f = t + it * 256;
        const int r = f >> 4, kq = f & 15;
        float4 v = *(const float4*)(emb + (size_t)(rblk * 64 + r) * E_ + k0 + kq * 4);
        *(float4*)&As[r][((kq ^ (r >> 2)) & 15) * 4] = v;
    }
#pragma unroll
    for (int it = 0; it < 4; ++it) {
        const int f = t + it * 256;
        const int c = f >> 4, kq = f & 15;
        float4 v = *(const float4*)(W + (size_t)(cblk * 64 + c) * E_ + k0 + kq * 4);
        const int pc = (((c >> 2) ^ kq) & 15) * 4 + (c & 3);
        Ws[kq * 4 + 0][pc] = v.x;
        Ws[kq * 4 + 1][pc] = v.y;
        Ws[kq * 4 + 2][pc] = v.z;
        Ws[kq * 4 + 3][pc] = v.w;
    }
    __syncthreads();

    const int tx = t & 15, ty = t >> 4;   // c-quad, r-quad
    const int c0 = tx * 4, r0 = ty * 4;

    float4 acc0 = {0, 0, 0, 0}, acc1 = {0, 0, 0, 0};
    float4 acc2 = {0, 0, 0, 0}, acc3 = {0, 0, 0, 0};

    for (int k = 0; k < 64; k += 4) {
        const int K  = k >> 2;
        const int ac = ((K ^ ty) & 15) * 4;
        const int wc = ((tx ^ K) & 15) * 4;
        float4 a0 = *(const float4*)&As[r0 + 0][ac];
        float4 a1 = *(const float4*)&As[r0 + 1][ac];
        float4 a2 = *(const float4*)&As[r0 + 2][ac];
        float4 a3 = *(const float4*)&As[r0 + 3][ac];
        float4 w0 = *(const float4*)&Ws[k + 0][wc];
        float4 w1 = *(const float4*)&Ws[k + 1][wc];
        float4 w2 = *(const float4*)&Ws[k + 2][wc];
        float4 w3 = *(const float4*)&Ws[k + 3][wc];
#define MLP_STEP(ACC, AV)                                                  \
        ACC.x = fmaf(AV.x, w0.x, fmaf(AV.y, w1.x, fmaf(AV.z, w2.x, fmaf(AV.w, w3.x, ACC.x)))); \
        ACC.y = fmaf(AV.x, w0.y, fmaf(AV.y, w1.y, fmaf(AV.z, w2.y, fmaf(AV.w, w3.y, ACC.y)))); \
        ACC.z = fmaf(AV.x, w0.z, fmaf(AV.y, w1.z, fmaf(AV.z, w2.z, fmaf(AV.w, w3.z, ACC.z)))); \
        ACC.w = fmaf(AV.x, w0.w, fmaf(AV.y, w1.w, fmaf(AV.z, w2.w, fmaf(AV.w, w3.w, ACC.w))));
        MLP_STEP(acc0, a0)
        MLP_STEP(acc1, a1)
        MLP_STEP(acc2, a2)
        MLP_STEP(acc3, a3)
#undef MLP_STEP
    }

    float* dst = part + ((size_t)kch * (B_ * H_) + rblk * 64 + r0) * E_ +
                 cblk * 64 + c0;
    *(float4*)(dst + 0 * E_) = acc0;
    *(float4*)(dst + 1 * E_) = acc1;
    *(float4*)(dst + 2 * E_) = acc2;
    *(float4*)(dst + 3 * E_) = acc3;
}

// ---------------------------------------------------------------------------
// Kernel 4: out = sum of KSPLIT partials + bias.
// ---------------------------------------------------------------------------
__global__ __launch_bounds__(256) void k_out(const float4* __restrict__ part,
                                             const float4* __restrict__ bias,
                                             float4* __restrict__ out) {
    const int idx = blockIdx.x * 256 + threadIdx.x;   // < 32768
    const int sl  = (B_ * H_ * E_) / 4;
    float4 s = part[idx];
#pragma unroll
    for (int j = 1; j < KSPLIT; ++j) {
        float4 p = part[(size_t)j * sl + idx];
        s.x += p.x; s.y += p.y; s.z += p.z; s.w += p.w;
    }
    float4 bv = bias[idx & (E_ / 4 - 1)];
    s.x += bv.x; s.y += bv.y; s.z += bv.z; s.w += bv.w;
    out[idx] = s;
}

extern "C" void kernel_launch(void* const* d_in, const int* in_sizes, int n_in,
                              void* d_out, int out_size, void* d_ws, size_t ws_size,
                              hipStream_t stream) {
    // setup_inputs order: x, W_q, W_k, W_v, mlp_w, mlp_b  (all fp32)
    const float* x     = (const float*)d_in[0];
    const float* W_v   = (const float*)d_in[3];
    const float* mlp_w = (const float*)d_in[4];
    const float* mlp_b = (const float*)d_in[5];
    float* out = (float*)d_out;

    // ws layout: emb partials (16 x 256 x 512 = 8 MB) | emb (512 KB) |
    //            mlp partials (8 x 256 x 512 = 4 MB)
    float* epart = (float*)d_ws;
    float* emb   = epart + (size_t)NSLICE * B_ * H_ * E_;
    float* mpart = emb + (size_t)B_ * H_ * E_;

    dim3 g1(E_ / 64, B_ / 8, (H_ / 8) * NSLICE);   // (8,2,32) = 512 blocks
    k_emb_part<<<g1, 256, 0, stream>>>(x, W_v, epart);

    k_emb_reduce<<<(B_ * H_ * E_ / 4) / 256, 256, 0, stream>>>(
        (const float4*)epart, (float4*)emb);

    dim3 g3(E_ / 64, (B_ * H_) / 64, KSPLIT);      // (8,4,8) = 256 blocks
    k_mlp_part<<<g3, 256, 0, stream>>>(emb, mlp_w, mpart);

    k_out<<<(B_ * H_ * E_ / 4) / 256, 256, 0, stream>>>(
        (const float4*)mpart, (const float4*)mlp_b, (float4*)out);
}